// Round 4
// baseline (2663.308 us; speedup 1.0000x reference)
//
#include <hip/hip_runtime.h>
#include <hip/hip_bf16.h>
#include <cstdint>
#include <cstddef>

#define EMB 128
#define NLIG 32768
#define NREC 262144
#define NGRAPH 1024
#define ELIG 327680
#define EREC 2097152
#define BN_EPS 1e-5f

typedef unsigned short ushort_t;
typedef short bf16x8 __attribute__((ext_vector_type(8)));
typedef float f32x4 __attribute__((ext_vector_type(4)));

__device__ __forceinline__ float bf2f(ushort_t u) {
  union { unsigned int i; float f; } v;
  v.i = ((unsigned int)u) << 16;
  return v.f;
}
__device__ __forceinline__ ushort_t f2bf(float f) {
  __hip_bfloat16 h = __float2bfloat16(f);  // RNE
  union { __hip_bfloat16 h; ushort_t u; } v;
  v.h = h;
  return v.u;
}

// ============================ CSR build ============================

__global__ __launch_bounds__(256)
void gk_count(const int* __restrict__ dst, int* __restrict__ cnt, int E) {
  int e = blockIdx.x * 256 + threadIdx.x;
  if (e < E) atomicAdd(&cnt[dst[e]], 1);
}

__global__ __launch_bounds__(256)
void gk_scan1(const int* __restrict__ cnt, int* __restrict__ off,
              int* __restrict__ bsum, int n) {
  __shared__ int sm[256];
  int t = threadIdx.x;
  int base = blockIdx.x * 1024 + t * 4;
  int v0 = (base + 0 < n) ? cnt[base + 0] : 0;
  int v1 = (base + 1 < n) ? cnt[base + 1] : 0;
  int v2 = (base + 2 < n) ? cnt[base + 2] : 0;
  int v3 = (base + 3 < n) ? cnt[base + 3] : 0;
  int loc = v0 + v1 + v2 + v3;
  sm[t] = loc;
  __syncthreads();
  for (int o = 1; o < 256; o <<= 1) {
    int x = (t >= o) ? sm[t - o] : 0;
    __syncthreads();
    sm[t] += x;
    __syncthreads();
  }
  int run = sm[t] - loc;
  if (base + 0 < n) off[base + 0] = run;
  run += v0;
  if (base + 1 < n) off[base + 1] = run;
  run += v1;
  if (base + 2 < n) off[base + 2] = run;
  run += v2;
  if (base + 3 < n) off[base + 3] = run;
  if (t == 255) bsum[blockIdx.x] = sm[255];
}

__global__ __launch_bounds__(256)
void gk_scan2(int* __restrict__ bsum, int nb) {
  __shared__ int sm[256];
  int t = threadIdx.x;
  int v = (t < nb) ? bsum[t] : 0;
  sm[t] = v;
  __syncthreads();
  for (int o = 1; o < 256; o <<= 1) {
    int x = (t >= o) ? sm[t - o] : 0;
    __syncthreads();
    sm[t] += x;
    __syncthreads();
  }
  if (t < nb) bsum[t] = sm[t] - v;
}

__global__ __launch_bounds__(256)
void gk_scan3(int* __restrict__ off, const int* __restrict__ bsum, int n, int E) {
  int i = blockIdx.x * 256 + threadIdx.x;
  if (i < n) off[i] += bsum[i >> 10];
  if (i == 0) off[n] = E;
}

__global__ __launch_bounds__(256)
void gk_copy(int* __restrict__ d, const int* __restrict__ s, int n) {
  int i = blockIdx.x * 256 + threadIdx.x;
  if (i < n) d[i] = s[i];
}

__global__ __launch_bounds__(256)
void gk_fill(const int* __restrict__ src, const int* __restrict__ dst,
             int* __restrict__ cur, int* __restrict__ csr, int E) {
  int e = blockIdx.x * 256 + threadIdx.x;
  if (e < E) {
    int d = dst[e];
    int pos = atomicAdd(&cur[d], 1);
    csr[pos] = src[e];
  }
}

__global__ __launch_bounds__(256)
void gk_dinv(const int* __restrict__ off, float* __restrict__ dinv, int n) {
  int i = blockIdx.x * 256 + threadIdx.x;
  if (i < n) dinv[i] = rsqrtf((float)(off[i + 1] - off[i] + 1));
}

// ============================ encoders ============================

__global__ __launch_bounds__(128)
void gk_ligenc(const int* __restrict__ lig_x, const int* __restrict__ offs,
               const float* __restrict__ emb, ushort_t* __restrict__ A) {
  __shared__ int idx[9];
  int i = blockIdx.x;
  int c = threadIdx.x;
  if (c < 9) idx[c] = lig_x[i * 9 + c] + offs[c];
  __syncthreads();
  float acc = 0.f;
#pragma unroll
  for (int f = 0; f < 9; ++f) acc += emb[(size_t)idx[f] * EMB + c];
  A[(size_t)i * EMB + c] = f2bf(acc);
}

// prep: W[199,128] fp32 -> W^T bf16 [128 cols][224 k], K zero-padded.
__global__ __launch_bounds__(256)
void gk_recw2(const float* __restrict__ W, ushort_t* __restrict__ Wt) {
  int idx = blockIdx.x * 256 + threadIdx.x;  // 128*224 = 28672 total
  if (idx < 128 * 224) {
    int c = idx / 224, k = idx - c * 224;
    Wt[idx] = (k < 199) ? f2bf(W[(size_t)k * 128 + c]) : (ushort_t)0;
  }
}

// streaming fp32 -> bf16 cast of X[262144][199] into row-padded [262144][200]
__global__ __launch_bounds__(256)
void gk_xcast(const float* __restrict__ X, ushort_t* __restrict__ Xb) {
  const int ITEMS = NREC * 25;  // 25 chunks of 8 bf16 per row
  int stride = gridDim.x * 256;
  for (int v = blockIdx.x * 256 + threadIdx.x; v < ITEMS; v += stride) {
    int row = v / 25, sub = v - row * 25;
    int k0 = sub * 8;
    const float* xr = X + (size_t)row * 199 + k0;
    ushort_t tmp[8];
#pragma unroll
    for (int j = 0; j < 8; ++j) {
      float f = (k0 + j < 199) ? xr[j] : 0.f;
      tmp[j] = f2bf(f);
    }
    *(uint4*)(Xb + (size_t)row * 200 + k0) = *(uint4*)tmp;
  }
}

// rec encoder GEMM, LDS-free / barrier-free (verified round 3):
__global__ __launch_bounds__(256)
void gk_recenc2(const ushort_t* __restrict__ Xb, const int* __restrict__ xi,
                const float* __restrict__ emb1, const ushort_t* __restrict__ Wt,
                const float* __restrict__ b, ushort_t* __restrict__ A) {
  int t = threadIdx.x;
  int row0 = blockIdx.x * 128;
  int w = t >> 6, lane = t & 63;
  int m = lane & 15, quad = lane >> 4;
  int rbase = w * 32;
  int rA = row0 + rbase + m;
  int rB = rA + 16;

  f32x4 acc[2][8];
#pragma unroll
  for (int rt = 0; rt < 2; ++rt)
#pragma unroll
    for (int ct = 0; ct < 8; ++ct) acc[rt][ct] = (f32x4){0.f, 0.f, 0.f, 0.f};

  const ushort_t* xpA = Xb + (size_t)rA * 200 + quad * 8;
  const ushort_t* xpB = Xb + (size_t)rB * 200 + quad * 8;
  const ushort_t* wp = Wt + (size_t)m * 224 + quad * 8;

  for (int ch = 0; ch < 7; ++ch) {
    bf16x8 a0 = *(const bf16x8*)(xpA + ch * 32);
    bf16x8 a1 = *(const bf16x8*)(xpB + ch * 32);
#pragma unroll
    for (int ct = 0; ct < 8; ++ct) {
      bf16x8 bb = *(const bf16x8*)(wp + (size_t)ct * 16 * 224 + ch * 32);
      acc[0][ct] = __builtin_amdgcn_mfma_f32_16x16x32_bf16(a0, bb, acc[0][ct], 0, 0, 0);
      acc[1][ct] = __builtin_amdgcn_mfma_f32_16x16x32_bf16(a1, bb, acc[1][ct], 0, 0, 0);
    }
  }

  float bcol[8];
#pragma unroll
  for (int ct = 0; ct < 8; ++ct) bcol[ct] = b[ct * 16 + m];
#pragma unroll
  for (int rt = 0; rt < 2; ++rt) {
    int rb = row0 + rbase + rt * 16 + quad * 4;
#pragma unroll
    for (int rr = 0; rr < 4; ++rr) {
      int row = rb + rr;
      const float* e = emb1 + (size_t)xi[row] * 128;
#pragma unroll
      for (int ct = 0; ct < 8; ++ct) {
        int c = ct * 16 + m;
        float v = acc[rt][ct][rr] + bcol[ct] + e[c];
        A[(size_t)row * 128 + c] = f2bf(v);
      }
    }
  }
}

// ======================= per-layer prep =======================
__global__ __launch_bounds__(256)
void gk_prep(const float* __restrict__ W, const float* __restrict__ stats,
             const float* __restrict__ gamma, const float* __restrict__ beta,
             float inv_n, int donorm, ushort_t* __restrict__ Wt,
             float* __restrict__ bnscl, float* __restrict__ bnsh) {
  int idx = blockIdx.x * 256 + threadIdx.x;
  if (idx < 128) {
    if (donorm) {
      float mu = stats[idx] * inv_n;
      float var = stats[128 + idx] * inv_n - mu * mu;
      float s = gamma[idx] * rsqrtf(var + BN_EPS);
      bnscl[idx] = s;
      bnsh[idx] = beta[idx] - mu * s;
    } else {
      bnscl[idx] = 1.f;
      bnsh[idx] = 0.f;
    }
  }
  int c = idx >> 7, k = idx & 127;
  Wt[(size_t)c * 128 + k] = f2bf(W[(size_t)k * 128 + c]);
}

// ====================== MFMA GCN GEMM (verified) ======================
__global__ __launch_bounds__(256)
void gk_mm(const ushort_t* __restrict__ Xb, const ushort_t* __restrict__ Wt,
           const float* __restrict__ bnscl, const float* __restrict__ bnsh,
           int donorm, const float* __restrict__ dinv,
           ushort_t* __restrict__ gb) {
  __shared__ ushort_t Xs[128 * 128];
  __shared__ ushort_t Ws[128 * 128];
  int t = threadIdx.x;
  int row0 = blockIdx.x * 128;

  for (int i = t; i < 2048; i += 256) {
    int r = i >> 4, cc = i & 15;
    union { uint4 v; ushort_t s[8]; } u;
    u.v = *(const uint4*)(Xb + (size_t)(row0 + r) * 128 + cc * 8);
    if (donorm) {
#pragma unroll
      for (int j = 0; j < 8; ++j) {
        int k = cc * 8 + j;
        float f = fmaf(bf2f(u.s[j]), bnscl[k], bnsh[k]);
        f = f > 0.f ? f : 0.f;
        u.s[j] = f2bf(f);
      }
    }
    *(uint4*)&Xs[r * 128 + ((cc ^ (r & 15)) * 8)] = u.v;
  }
  for (int i = t; i < 2048; i += 256) {
    int c = i >> 4, cc = i & 15;
    uint4 u = *(const uint4*)(Wt + (size_t)c * 128 + cc * 8);
    *(uint4*)&Ws[c * 128 + ((cc ^ (c & 15)) * 8)] = u;
  }
  __syncthreads();

  int w = t >> 6, lane = t & 63;
  int m = lane & 15, quad = lane >> 4;
  int rbase = w * 32;

  f32x4 acc[2][8];
#pragma unroll
  for (int rt = 0; rt < 2; ++rt)
#pragma unroll
    for (int ct = 0; ct < 8; ++ct) acc[rt][ct] = (f32x4){0.f, 0.f, 0.f, 0.f};

#pragma unroll
  for (int kc8 = 0; kc8 < 16; kc8 += 4) {
    int ck = (kc8 + quad) ^ m;
    bf16x8 a0 = *(const bf16x8*)&Xs[(rbase + m) * 128 + ck * 8];
    bf16x8 a1 = *(const bf16x8*)&Xs[(rbase + 16 + m) * 128 + ck * 8];
#pragma unroll
    for (int ct = 0; ct < 8; ++ct) {
      bf16x8 b = *(const bf16x8*)&Ws[(ct * 16 + m) * 128 + ck * 8];
      acc[0][ct] = __builtin_amdgcn_mfma_f32_16x16x32_bf16(a0, b, acc[0][ct], 0, 0, 0);
      acc[1][ct] = __builtin_amdgcn_mfma_f32_16x16x32_bf16(a1, b, acc[1][ct], 0, 0, 0);
    }
  }

#pragma unroll
  for (int rt = 0; rt < 2; ++rt) {
    int rb = row0 + rbase + rt * 16 + quad * 4;
    float d0 = dinv[rb + 0], d1 = dinv[rb + 1];
    float d2 = dinv[rb + 2], d3 = dinv[rb + 3];
#pragma unroll
    for (int ct = 0; ct < 8; ++ct) {
      int c = ct * 16 + m;
      gb[(size_t)(rb + 0) * 128 + c] = f2bf(acc[rt][ct][0] * d0);
      gb[(size_t)(rb + 1) * 128 + c] = f2bf(acc[rt][ct][1] * d1);
      gb[(size_t)(rb + 2) * 128 + c] = f2bf(acc[rt][ct][2] * d2);
      gb[(size_t)(rb + 3) * 128 + c] = f2bf(acc[rt][ct][3] * d3);
    }
  }
}

// ---------------- aggregation (v2: 4 rows/wave, 8B gathers) ----------------

struct Quad {
  int i[4];
  float m[4];
};

__device__ __forceinline__ Quad load_quad(const int* __restrict__ csr,
                                          int e, int e1, int safe) {
  Quad q;
#pragma unroll
  for (int j = 0; j < 4; ++j) {
    int c = (e + j < e1) ? e + j : safe;
    q.i[j] = csr[c];
    q.m[j] = (e + j < e1) ? 1.f : 0.f;
  }
  return q;
}

__device__ __forceinline__ void gather4w(const ushort_t* __restrict__ g, int c0,
                                         const Quad& q, uint2* v) {
#pragma unroll
  for (int j = 0; j < 4; ++j)
    v[j] = *(const uint2*)(g + (size_t)q.i[j] * 128 + c0);
}

__device__ __forceinline__ void consume4w(float* acc, const Quad& q,
                                          const uint2* v) {
#pragma unroll
  for (int j = 0; j < 4; ++j) {
    float x0 = bf2f((ushort_t)(v[j].x & 0xffffu));
    float x1 = bf2f((ushort_t)(v[j].x >> 16));
    float x2 = bf2f((ushort_t)(v[j].y & 0xffffu));
    float x3 = bf2f((ushort_t)(v[j].y >> 16));
    acc[0] = fmaf(x0, q.m[j], acc[0]);
    acc[1] = fmaf(x1, q.m[j], acc[1]);
    acc[2] = fmaf(x2, q.m[j], acc[2]);
    acc[3] = fmaf(x3, q.m[j], acc[3]);
  }
}

// out[i] = dinv[i]*(g[i] + sum_{e in CSR[i]} g[src_e]) ; bf16 in/out, fp32
// accumulate + BN stats. Each wave handles FOUR rows concurrently:
// half-wave h owns rows (u, u+1); each lane covers 4 columns via uint2 (8B)
// gathers -> 8 gathers x 8B = 64B/lane in flight, ~2x fewer dependent
// memory round-trips than the 2-row version.
__global__ __launch_bounds__(256)
void gk_agg(const ushort_t* __restrict__ g, const int* __restrict__ off,
            const int* __restrict__ csr, const float* __restrict__ dinv,
            ushort_t* __restrict__ outb, float* __restrict__ stats) {
  __shared__ float ls[128];
  __shared__ float lss[128];
  int t = threadIdx.x;
  int w = t >> 6;            // wave 0..3
  int lane = t & 63;
  int h = lane >> 5;         // half 0/1
  int sl = lane & 31;
  int c0 = sl * 4;           // 4 bf16 cols per lane
  int r0 = blockIdx.x * 16 + w * 4;   // wave's 4 rows

  if (t < 128) { ls[t] = 0.f; lss[t] = 0.f; }
  __syncthreads();

  // wave-uniform offsets (scalarizable)
  int o0 = off[r0 + 0], o1 = off[r0 + 1], o2 = off[r0 + 2];
  int o3 = off[r0 + 3], o4 = off[r0 + 4];
  int maxd = max(max(o1 - o0, o2 - o1), max(o3 - o2, o4 - o3));

  // half-local rows u, v
  int u = r0 + h * 2;
  int v = u + 1;
  int eU = h ? o2 : o0, eU1 = h ? o3 : o1;
  int eV = h ? o3 : o1, eV1 = h ? o4 : o2;
  float dU = dinv[u], dV = dinv[v];

  // self rows (8B each)
  uint2 sU = *(const uint2*)(g + (size_t)u * 128 + c0);
  uint2 sV = *(const uint2*)(g + (size_t)v * 128 + c0);
  float accU[4], accV[4];
  accU[0] = bf2f((ushort_t)(sU.x & 0xffffu));
  accU[1] = bf2f((ushort_t)(sU.x >> 16));
  accU[2] = bf2f((ushort_t)(sU.y & 0xffffu));
  accU[3] = bf2f((ushort_t)(sU.y >> 16));
  accV[0] = bf2f((ushort_t)(sV.x & 0xffffu));
  accV[1] = bf2f((ushort_t)(sV.x >> 16));
  accV[2] = bf2f((ushort_t)(sV.y & 0xffffu));
  accV[3] = bf2f((ushort_t)(sV.y >> 16));

  int safeU = (eU1 > eU) ? eU1 - 1 : 0;
  int safeV = (eV1 > eV) ? eV1 - 1 : 0;

  // prologue: quad 0 for both rows of this half
  Quad qU = load_quad(csr, eU, eU1, safeU);
  Quad qV = load_quad(csr, eV, eV1, safeV);
  uint2 vU[4], vV[4];
  gather4w(g, c0, qU, vU);
  gather4w(g, c0, qV, vV);
  int eUc = eU + 4, eVc = eV + 4;

  // wave-uniform trip count: ceil(maxd/4) - 1 additional quads
  int rem = (maxd > 4) ? ((maxd - 1) >> 2) : 0;
  for (int it = 0; it < rem; ++it) {
    Quad nU = load_quad(csr, eUc, eU1, safeU);
    Quad nV = load_quad(csr, eVc, eV1, safeV);
    uint2 wU[4], wV[4];
    gather4w(g, c0, nU, wU);
    gather4w(g, c0, nV, wV);
    consume4w(accU, qU, vU);
    consume4w(accV, qV, vV);
    qU = nU; qV = nV;
#pragma unroll
    for (int j = 0; j < 4; ++j) { vU[j] = wU[j]; vV[j] = wV[j]; }
    eUc += 4; eVc += 4;
  }
  consume4w(accU, qU, vU);
  consume4w(accV, qV, vV);

  // scale, write, stats
  float sx[4], ssx[4];
#pragma unroll
  for (int k = 0; k < 4; ++k) {
    accU[k] *= dU; accV[k] *= dV;
    sx[k] = accU[k] + accV[k];
    ssx[k] = fmaf(accU[k], accU[k], accV[k] * accV[k]);
  }
  uint2 oU, oV;
  oU.x = (unsigned int)f2bf(accU[0]) | ((unsigned int)f2bf(accU[1]) << 16);
  oU.y = (unsigned int)f2bf(accU[2]) | ((unsigned int)f2bf(accU[3]) << 16);
  oV.x = (unsigned int)f2bf(accV[0]) | ((unsigned int)f2bf(accV[1]) << 16);
  oV.y = (unsigned int)f2bf(accV[2]) | ((unsigned int)f2bf(accV[3]) << 16);
  *(uint2*)(outb + (size_t)u * 128 + c0) = oU;
  *(uint2*)(outb + (size_t)v * 128 + c0) = oV;

#pragma unroll
  for (int k = 0; k < 4; ++k) {
    atomicAdd(&ls[c0 + k], sx[k]);
    atomicAdd(&lss[c0 + k], ssx[k]);
  }
  __syncthreads();
  if (t < 128) {
    atomicAdd(&stats[t], ls[t]);
    atomicAdd(&stats[t + 128], lss[t]);
  }
}

// per-graph mean of relu(bn(A_bf)) for the last layer
__global__ __launch_bounds__(128)
void gk_pool(const ushort_t* __restrict__ A, const float* __restrict__ stats,
             const float* __restrict__ gamma, const float* __restrict__ beta,
             float inv_n, float* __restrict__ z, int npg, int zoff) {
  int gidx = blockIdx.x;
  int c = threadIdx.x;
  float mu = stats[c] * inv_n;
  float var = stats[128 + c] * inv_n - mu * mu;
  float scl = gamma[c] * rsqrtf(var + BN_EPS);
  float be = beta[c];
  float sum = 0.f;
  int r0 = gidx * npg;
  for (int r = 0; r < npg; ++r) {
    float v = (bf2f(A[(size_t)(r0 + r) * 128 + c]) - mu) * scl + be;
    sum += v > 0.f ? v : 0.f;
  }
  z[(size_t)gidx * 256 + zoff + c] = sum * (1.0f / (float)npg);
}

__global__ __launch_bounds__(128)
void gk_mlp(const float* __restrict__ z, const float* __restrict__ w1,
            const float* __restrict__ b1, const float* __restrict__ w2,
            const float* __restrict__ b2, float* __restrict__ out) {
  __shared__ float zs[256];
  __shared__ float red[128];
  int gidx = blockIdx.x, t = threadIdx.x;
  zs[t] = z[(size_t)gidx * 256 + t];
  zs[t + 128] = z[(size_t)gidx * 256 + 128 + t];
  __syncthreads();
  float acc = b1[t];
  for (int k = 0; k < 256; ++k) acc += zs[k] * w1[(size_t)k * 128 + t];
  acc = (acc > 0.f ? acc : 0.f) * w2[t];
  red[t] = acc;
  __syncthreads();
  for (int o = 64; o > 0; o >>= 1) {
    if (t < o) red[t] += red[t + o];
    __syncthreads();
  }
  if (t == 0) out[gidx] = red[0] + b2[0];
}

// ============================ launch ============================

extern "C" void kernel_launch(void* const* d_in, const int* in_sizes, int n_in,
                              void* d_out, int out_size, void* d_ws, size_t ws_size,
                              hipStream_t stream) {
  (void)in_sizes; (void)n_in; (void)out_size; (void)ws_size;
  const int*   lig_x       = (const int*)  d_in[0];
  const int*   rec_x_int   = (const int*)  d_in[1];
  const float* rec_x_float = (const float*)d_in[2];
  const int*   lig_ei      = (const int*)  d_in[3];
  const int*   rec_ei      = (const int*)  d_in[4];
  const int*   atom_off    = (const int*)  d_in[7];
  const float* atom_emb    = (const float*)d_in[8];
  const float* rec_emb1    = (const float*)d_in[9];
  const float* rec_w       = (const float*)d_in[10];
  const float* rec_b       = (const float*)d_in[11];
  const float* lig_W       = (const float*)d_in[12];
  const float* lig_gamma   = (const float*)d_in[14];
  const float* lig_beta    = (const float*)d_in[15];
  const float* rec_W       = (const float*)d_in[16];
  const float* rec_gamma   = (const float*)d_in[18];
  const float* rec_beta    = (const float*)d_in[19];
  const float* out_w1      = (const float*)d_in[20];
  const float* out_b1      = (const float*)d_in[21];
  const float* out_w2      = (const float*)d_in[22];
  const float* out_b2      = (const float*)d_in[23];
  float* out = (float*)d_out;

  char* p = (char*)d_ws;
  auto alloc = [&](size_t bytes) -> void* {
    void* r = p;
    p += (bytes + 255) & ~(size_t)255;
    return r;
  };
  ushort_t* Ab     = (ushort_t*)alloc((size_t)NREC * EMB * 2);  // features bf16
  ushort_t* Gb     = (ushort_t*)alloc((size_t)NREC * EMB * 2);  // g bf16
  ushort_t* Wtb    = (ushort_t*)alloc((size_t)EMB * EMB * 2);   // W^T bf16
  ushort_t* WtK    = (ushort_t*)alloc((size_t)EMB * 224 * 2);   // rec_w^T bf16, K-padded
  ushort_t* Xb2    = (ushort_t*)alloc(((size_t)NREC * 200 + 64) * 2);  // bf16 X, padded rows
  float* bnscl     = (float*)alloc(128 * 4);
  float* bnsh      = (float*)alloc(128 * 4);
  float* dinv_lig  = (float*)alloc((size_t)NLIG * 4);
  float* dinv_rec  = (float*)alloc((size_t)NREC * 4);
  int*   cnt_lig   = (int*)  alloc((size_t)NLIG * 4);
  int*   cnt_rec   = (int*)  alloc((size_t)NREC * 4);
  int*   off_lig   = (int*)  alloc((size_t)(NLIG + 8) * 4);
  int*   off_rec   = (int*)  alloc((size_t)(NREC + 8) * 4);
  int*   csr_lig   = (int*)  alloc((size_t)ELIG * 4);
  int*   csr_rec   = (int*)  alloc((size_t)EREC * 4);
  int*   bsum_lig  = (int*)  alloc(256 * 4);
  int*   bsum_rec  = (int*)  alloc(256 * 4);
  float* stats     = (float*)alloc(256 * 4);
  float* z         = (float*)alloc((size_t)NGRAPH * 256 * 4);

  // ---- CSR build ----
  hipMemsetAsync(cnt_lig, 0, (size_t)NLIG * 4, stream);
  hipMemsetAsync(cnt_rec, 0, (size_t)NREC * 4, stream);
  // off[n..n+4] = E so the agg kernel's off[r0+4] read stays in-bounds & valid
  hipMemsetAsync(off_lig + NLIG + 1, 0, 7 * 4, stream);
  hipMemsetAsync(off_rec + NREC + 1, 0, 7 * 4, stream);
  gk_count<<<ELIG / 256, 256, 0, stream>>>(lig_ei + ELIG, cnt_lig, ELIG);
  gk_count<<<EREC / 256, 256, 0, stream>>>(rec_ei + EREC, cnt_rec, EREC);
  gk_scan1<<<NLIG / 1024, 256, 0, stream>>>(cnt_lig, off_lig, bsum_lig, NLIG);
  gk_scan2<<<1, 256, 0, stream>>>(bsum_lig, NLIG / 1024);
  gk_scan3<<<NLIG / 256, 256, 0, stream>>>(off_lig, bsum_lig, NLIG, ELIG);
  gk_scan1<<<NREC / 1024, 256, 0, stream>>>(cnt_rec, off_rec, bsum_rec, NREC);
  gk_scan2<<<1, 256, 0, stream>>>(bsum_rec, NREC / 1024);
  gk_scan3<<<NREC / 256, 256, 0, stream>>>(off_rec, bsum_rec, NREC, EREC);
  gk_copy<<<NLIG / 256, 256, 0, stream>>>(cnt_lig, off_lig, NLIG);
  gk_copy<<<NREC / 256, 256, 0, stream>>>(cnt_rec, off_rec, NREC);
  gk_fill<<<ELIG / 256, 256, 0, stream>>>(lig_ei, lig_ei + ELIG, cnt_lig, csr_lig, ELIG);
  gk_fill<<<EREC / 256, 256, 0, stream>>>(rec_ei, rec_ei + EREC, cnt_rec, csr_rec, EREC);
  gk_dinv<<<NLIG / 256, 256, 0, stream>>>(off_lig, dinv_lig, NLIG);
  gk_dinv<<<NREC / 256, 256, 0, stream>>>(off_rec, dinv_rec, NREC);

  auto run_entity = [&](const float* Wall, const float* gamma, const float* beta,
                        const int* offv, const int* csrv, const float* dinv,
                        int n, int npg, int zoff) {
    float inv_n = 1.0f / (float)n;
    for (int l = 0; l < 3; ++l) {
      const float* W = Wall + (size_t)l * EMB * EMB;
      const float* gm = (l > 0) ? gamma + (size_t)(l - 1) * EMB : gamma;
      const float* bt = (l > 0) ? beta + (size_t)(l - 1) * EMB : beta;
      gk_prep<<<64, 256, 0, stream>>>(W, stats, gm, bt, inv_n, l > 0 ? 1 : 0,
                                      Wtb, bnscl, bnsh);
      hipMemsetAsync(stats, 0, 256 * 4, stream);
      gk_mm<<<n / 128, 256, 0, stream>>>(Ab, Wtb, bnscl, bnsh, l > 0 ? 1 : 0,
                                         dinv, Gb);
      gk_agg<<<n / 16, 256, 0, stream>>>(Gb, offv, csrv, dinv, Ab, stats);
    }
    gk_pool<<<NGRAPH, 128, 0, stream>>>(Ab, stats, gamma + 2 * EMB, beta + 2 * EMB,
                                        inv_n, z, npg, zoff);
  };

  // ---- ligand path ----
  gk_ligenc<<<NLIG, 128, 0, stream>>>(lig_x, atom_off, atom_emb, Ab);
  run_entity(lig_W, lig_gamma, lig_beta, off_lig, csr_lig, dinv_lig,
             NLIG, NLIG / NGRAPH, 0);

  // ---- receptor path ----
  gk_recw2<<<112, 256, 0, stream>>>(rec_w, WtK);
  gk_xcast<<<2048, 256, 0, stream>>>(rec_x_float, Xb2);
  gk_recenc2<<<NREC / 128, 256, 0, stream>>>(Xb2, rec_x_int, rec_emb1,
                                             WtK, rec_b, Ab);
  run_entity(rec_W, rec_gamma, rec_beta, off_rec, csr_rec, dinv_rec,
             NREC, NREC / NGRAPH, EMB);

  // ---- head ----
  gk_mlp<<<NGRAPH, 128, 0, stream>>>(z, out_w1, out_b1, out_w2, out_b2, out);
}

// Round 5
// 1878.838 us; speedup vs baseline: 1.4175x; 1.4175x over previous
//
#include <hip/hip_runtime.h>
#include <hip/hip_bf16.h>
#include <cstdint>
#include <cstddef>

#define EMB 128
#define NLIG 32768
#define NREC 262144
#define NGRAPH 1024
#define ELIG 327680
#define EREC 2097152
#define BN_EPS 1e-5f

typedef unsigned short ushort_t;
typedef short bf16x8 __attribute__((ext_vector_type(8)));
typedef float f32x4 __attribute__((ext_vector_type(4)));

__device__ __forceinline__ float bf2f(ushort_t u) {
  union { unsigned int i; float f; } v;
  v.i = ((unsigned int)u) << 16;
  return v.f;
}
__device__ __forceinline__ ushort_t f2bf(float f) {
  __hip_bfloat16 h = __float2bfloat16(f);  // RNE
  union { __hip_bfloat16 h; ushort_t u; } v;
  v.h = h;
  return v.u;
}

// ============================ CSR build ============================

__global__ __launch_bounds__(256)
void gk_count(const int* __restrict__ dst, int* __restrict__ cnt, int E) {
  int e = blockIdx.x * 256 + threadIdx.x;
  if (e < E) atomicAdd(&cnt[dst[e]], 1);
}

__global__ __launch_bounds__(256)
void gk_scan1(const int* __restrict__ cnt, int* __restrict__ off,
              int* __restrict__ bsum, int n) {
  __shared__ int sm[256];
  int t = threadIdx.x;
  int base = blockIdx.x * 1024 + t * 4;
  int v0 = (base + 0 < n) ? cnt[base + 0] : 0;
  int v1 = (base + 1 < n) ? cnt[base + 1] : 0;
  int v2 = (base + 2 < n) ? cnt[base + 2] : 0;
  int v3 = (base + 3 < n) ? cnt[base + 3] : 0;
  int loc = v0 + v1 + v2 + v3;
  sm[t] = loc;
  __syncthreads();
  for (int o = 1; o < 256; o <<= 1) {
    int x = (t >= o) ? sm[t - o] : 0;
    __syncthreads();
    sm[t] += x;
    __syncthreads();
  }
  int run = sm[t] - loc;
  if (base + 0 < n) off[base + 0] = run;
  run += v0;
  if (base + 1 < n) off[base + 1] = run;
  run += v1;
  if (base + 2 < n) off[base + 2] = run;
  run += v2;
  if (base + 3 < n) off[base + 3] = run;
  if (t == 255) bsum[blockIdx.x] = sm[255];
}

__global__ __launch_bounds__(256)
void gk_scan2(int* __restrict__ bsum, int nb) {
  __shared__ int sm[256];
  int t = threadIdx.x;
  int v = (t < nb) ? bsum[t] : 0;
  sm[t] = v;
  __syncthreads();
  for (int o = 1; o < 256; o <<= 1) {
    int x = (t >= o) ? sm[t - o] : 0;
    __syncthreads();
    sm[t] += x;
    __syncthreads();
  }
  if (t < nb) bsum[t] = sm[t] - v;
}

__global__ __launch_bounds__(256)
void gk_scan3(int* __restrict__ off, const int* __restrict__ bsum, int n, int E) {
  int i = blockIdx.x * 256 + threadIdx.x;
  if (i < n) off[i] += bsum[i >> 10];
  if (i == 0) off[n] = E;
}

__global__ __launch_bounds__(256)
void gk_copy(int* __restrict__ d, const int* __restrict__ s, int n) {
  int i = blockIdx.x * 256 + threadIdx.x;
  if (i < n) d[i] = s[i];
}

__global__ __launch_bounds__(256)
void gk_fill(const int* __restrict__ src, const int* __restrict__ dst,
             int* __restrict__ cur, int* __restrict__ csr, int E) {
  int e = blockIdx.x * 256 + threadIdx.x;
  if (e < E) {
    int d = dst[e];
    int pos = atomicAdd(&cur[d], 1);
    csr[pos] = src[e];
  }
}

__global__ __launch_bounds__(256)
void gk_dinv(const int* __restrict__ off, float* __restrict__ dinv, int n) {
  int i = blockIdx.x * 256 + threadIdx.x;
  if (i < n) dinv[i] = rsqrtf((float)(off[i + 1] - off[i] + 1));
}

// ============================ encoders ============================

__global__ __launch_bounds__(128)
void gk_ligenc(const int* __restrict__ lig_x, const int* __restrict__ offs,
               const float* __restrict__ emb, ushort_t* __restrict__ A) {
  __shared__ int idx[9];
  int i = blockIdx.x;
  int c = threadIdx.x;
  if (c < 9) idx[c] = lig_x[i * 9 + c] + offs[c];
  __syncthreads();
  float acc = 0.f;
#pragma unroll
  for (int f = 0; f < 9; ++f) acc += emb[(size_t)idx[f] * EMB + c];
  A[(size_t)i * EMB + c] = f2bf(acc);
}

// prep: W[199,128] fp32 -> W^T bf16 [128 cols][224 k], K zero-padded.
__global__ __launch_bounds__(256)
void gk_recw2(const float* __restrict__ W, ushort_t* __restrict__ Wt) {
  int idx = blockIdx.x * 256 + threadIdx.x;  // 128*224 = 28672 total
  if (idx < 128 * 224) {
    int c = idx / 224, k = idx - c * 224;
    Wt[idx] = (k < 199) ? f2bf(W[(size_t)k * 128 + c]) : (ushort_t)0;
  }
}

// streaming fp32 -> bf16 cast of X[262144][199] into row-padded [262144][200]
__global__ __launch_bounds__(256)
void gk_xcast(const float* __restrict__ X, ushort_t* __restrict__ Xb) {
  const int ITEMS = NREC * 25;  // 25 chunks of 8 bf16 per row
  int stride = gridDim.x * 256;
  for (int v = blockIdx.x * 256 + threadIdx.x; v < ITEMS; v += stride) {
    int row = v / 25, sub = v - row * 25;
    int k0 = sub * 8;
    const float* xr = X + (size_t)row * 199 + k0;
    ushort_t tmp[8];
#pragma unroll
    for (int j = 0; j < 8; ++j) {
      float f = (k0 + j < 199) ? xr[j] : 0.f;
      tmp[j] = f2bf(f);
    }
    *(uint4*)(Xb + (size_t)row * 200 + k0) = *(uint4*)tmp;
  }
}

// rec encoder GEMM, LDS-free / barrier-free (verified round 3):
__global__ __launch_bounds__(256)
void gk_recenc2(const ushort_t* __restrict__ Xb, const int* __restrict__ xi,
                const float* __restrict__ emb1, const ushort_t* __restrict__ Wt,
                const float* __restrict__ b, ushort_t* __restrict__ A) {
  int t = threadIdx.x;
  int row0 = blockIdx.x * 128;
  int w = t >> 6, lane = t & 63;
  int m = lane & 15, quad = lane >> 4;
  int rbase = w * 32;
  int rA = row0 + rbase + m;
  int rB = rA + 16;

  f32x4 acc[2][8];
#pragma unroll
  for (int rt = 0; rt < 2; ++rt)
#pragma unroll
    for (int ct = 0; ct < 8; ++ct) acc[rt][ct] = (f32x4){0.f, 0.f, 0.f, 0.f};

  const ushort_t* xpA = Xb + (size_t)rA * 200 + quad * 8;
  const ushort_t* xpB = Xb + (size_t)rB * 200 + quad * 8;
  const ushort_t* wp = Wt + (size_t)m * 224 + quad * 8;

  for (int ch = 0; ch < 7; ++ch) {
    bf16x8 a0 = *(const bf16x8*)(xpA + ch * 32);
    bf16x8 a1 = *(const bf16x8*)(xpB + ch * 32);
#pragma unroll
    for (int ct = 0; ct < 8; ++ct) {
      bf16x8 bb = *(const bf16x8*)(wp + (size_t)ct * 16 * 224 + ch * 32);
      acc[0][ct] = __builtin_amdgcn_mfma_f32_16x16x32_bf16(a0, bb, acc[0][ct], 0, 0, 0);
      acc[1][ct] = __builtin_amdgcn_mfma_f32_16x16x32_bf16(a1, bb, acc[1][ct], 0, 0, 0);
    }
  }

  float bcol[8];
#pragma unroll
  for (int ct = 0; ct < 8; ++ct) bcol[ct] = b[ct * 16 + m];
#pragma unroll
  for (int rt = 0; rt < 2; ++rt) {
    int rb = row0 + rbase + rt * 16 + quad * 4;
#pragma unroll
    for (int rr = 0; rr < 4; ++rr) {
      int row = rb + rr;
      const float* e = emb1 + (size_t)xi[row] * 128;
#pragma unroll
      for (int ct = 0; ct < 8; ++ct) {
        int c = ct * 16 + m;
        float v = acc[rt][ct][rr] + bcol[ct] + e[c];
        A[(size_t)row * 128 + c] = f2bf(v);
      }
    }
  }
}

// ======================= per-layer prep =======================
__global__ __launch_bounds__(256)
void gk_prep(const float* __restrict__ W, const float* __restrict__ stats,
             const float* __restrict__ gamma, const float* __restrict__ beta,
             float inv_n, int donorm, ushort_t* __restrict__ Wt,
             float* __restrict__ bnscl, float* __restrict__ bnsh) {
  int idx = blockIdx.x * 256 + threadIdx.x;
  if (idx < 128) {
    if (donorm) {
      float mu = stats[idx] * inv_n;
      float var = stats[128 + idx] * inv_n - mu * mu;
      float s = gamma[idx] * rsqrtf(var + BN_EPS);
      bnscl[idx] = s;
      bnsh[idx] = beta[idx] - mu * s;
    } else {
      bnscl[idx] = 1.f;
      bnsh[idx] = 0.f;
    }
  }
  int c = idx >> 7, k = idx & 127;
  Wt[(size_t)c * 128 + k] = f2bf(W[(size_t)k * 128 + c]);
}

// ====================== MFMA GCN GEMM (verified) ======================
__global__ __launch_bounds__(256)
void gk_mm(const ushort_t* __restrict__ Xb, const ushort_t* __restrict__ Wt,
           const float* __restrict__ bnscl, const float* __restrict__ bnsh,
           int donorm, const float* __restrict__ dinv,
           ushort_t* __restrict__ gb) {
  __shared__ ushort_t Xs[128 * 128];
  __shared__ ushort_t Ws[128 * 128];
  int t = threadIdx.x;
  int row0 = blockIdx.x * 128;

  for (int i = t; i < 2048; i += 256) {
    int r = i >> 4, cc = i & 15;
    union { uint4 v; ushort_t s[8]; } u;
    u.v = *(const uint4*)(Xb + (size_t)(row0 + r) * 128 + cc * 8);
    if (donorm) {
#pragma unroll
      for (int j = 0; j < 8; ++j) {
        int k = cc * 8 + j;
        float f = fmaf(bf2f(u.s[j]), bnscl[k], bnsh[k]);
        f = f > 0.f ? f : 0.f;
        u.s[j] = f2bf(f);
      }
    }
    *(uint4*)&Xs[r * 128 + ((cc ^ (r & 15)) * 8)] = u.v;
  }
  for (int i = t; i < 2048; i += 256) {
    int c = i >> 4, cc = i & 15;
    uint4 u = *(const uint4*)(Wt + (size_t)c * 128 + cc * 8);
    *(uint4*)&Ws[c * 128 + ((cc ^ (c & 15)) * 8)] = u;
  }
  __syncthreads();

  int w = t >> 6, lane = t & 63;
  int m = lane & 15, quad = lane >> 4;
  int rbase = w * 32;

  f32x4 acc[2][8];
#pragma unroll
  for (int rt = 0; rt < 2; ++rt)
#pragma unroll
    for (int ct = 0; ct < 8; ++ct) acc[rt][ct] = (f32x4){0.f, 0.f, 0.f, 0.f};

#pragma unroll
  for (int kc8 = 0; kc8 < 16; kc8 += 4) {
    int ck = (kc8 + quad) ^ m;
    bf16x8 a0 = *(const bf16x8*)&Xs[(rbase + m) * 128 + ck * 8];
    bf16x8 a1 = *(const bf16x8*)&Xs[(rbase + 16 + m) * 128 + ck * 8];
#pragma unroll
    for (int ct = 0; ct < 8; ++ct) {
      bf16x8 b = *(const bf16x8*)&Ws[(ct * 16 + m) * 128 + ck * 8];
      acc[0][ct] = __builtin_amdgcn_mfma_f32_16x16x32_bf16(a0, b, acc[0][ct], 0, 0, 0);
      acc[1][ct] = __builtin_amdgcn_mfma_f32_16x16x32_bf16(a1, b, acc[1][ct], 0, 0, 0);
    }
  }

#pragma unroll
  for (int rt = 0; rt < 2; ++rt) {
    int rb = row0 + rbase + rt * 16 + quad * 4;
    float d0 = dinv[rb + 0], d1 = dinv[rb + 1];
    float d2 = dinv[rb + 2], d3 = dinv[rb + 3];
#pragma unroll
    for (int ct = 0; ct < 8; ++ct) {
      int c = ct * 16 + m;
      gb[(size_t)(rb + 0) * 128 + c] = f2bf(acc[rt][ct][0] * d0);
      gb[(size_t)(rb + 1) * 128 + c] = f2bf(acc[rt][ct][1] * d1);
      gb[(size_t)(rb + 2) * 128 + c] = f2bf(acc[rt][ct][2] * d2);
      gb[(size_t)(rb + 3) * 128 + c] = f2bf(acc[rt][ct][3] * d3);
    }
  }
}

// ---------------- aggregation (v3: hoisted csr, shfl-distributed) ----------------
// Key idea: all edge-index loads are hoisted out of the gather loop. One
// coalesced load per row (lane j loads csr[e+j]) covers the first 64 edges;
// per-edge indices are distributed via __shfl (VALU only). The gather loop
// then has NO address-dependent memory reads -> partial vmcnt waits, deep
// gather pipelining. deg>64 handled by a (practically never taken) tail.

__device__ __forceinline__ void gather8(const ushort_t* __restrict__ g, int c0,
                                        int idxv, int q, unsigned int* v) {
#pragma unroll
  for (int k = 0; k < 8; ++k) {
    int idx = __shfl(idxv, q * 8 + k);
    v[k] = *(const unsigned int*)(g + (size_t)idx * 128 + c0);
  }
}

__device__ __forceinline__ void consume8(float2& acc, const unsigned int* v,
                                         int q, int deg) {
#pragma unroll
  for (int k = 0; k < 8; ++k) {
    float m = (q * 8 + k < deg) ? 1.f : 0.f;
    acc.x = fmaf(bf2f((ushort_t)(v[k] & 0xffffu)), m, acc.x);
    acc.y = fmaf(bf2f((ushort_t)(v[k] >> 16)), m, acc.y);
  }
}

// out[i] = dinv[i]*(g[i] + sum_{e in CSR[i]} g[src_e]) ; bf16 in/out, fp32
// accumulate + BN stats. Wave handles 2 rows x 4 phases (as round-3), but
// offsets (1 coalesced load) and all 8 rows' edge indices (8 coalesced loads)
// are hoisted to the wave prologue.
__global__ __launch_bounds__(256)
void gk_agg(const ushort_t* __restrict__ g, const int* __restrict__ off,
            const int* __restrict__ csr, const float* __restrict__ dinv,
            ushort_t* __restrict__ outb, float* __restrict__ stats) {
  __shared__ float ls[128];
  __shared__ float lss[128];
  int t = threadIdx.x;
  int slot = t >> 6;        // 4 waves per block
  int lane = t & 63;
  int c0 = lane * 2;
  int i0 = blockIdx.x * 32;

  if (t < 128) { ls[t] = 0.f; lss[t] = 0.f; }
  __syncthreads();

  // one coalesced load covers off[i0 .. i0+32]
  int offv = off[i0 + min(lane, 32)];

  // hoist first-64 edge indices for all 4 phases (8 coalesced loads)
  int idxA[4], idxB[4], dAs[4], dBs[4];
#pragma unroll
  for (int p = 0; p < 4; ++p) {
    int base = slot * 2 + p * 8;
    int eA  = __shfl(offv, base + 0);
    int eB  = __shfl(offv, base + 1);
    int eB1 = __shfl(offv, base + 2);
    dAs[p] = eB - eA;
    dBs[p] = eB1 - eB;
    int adrA = (dAs[p] > 0) ? min(eA + lane, eB - 1) : 0;
    int adrB = (dBs[p] > 0) ? min(eB + lane, eB1 - 1) : 0;
    idxA[p] = csr[adrA];
    idxB[p] = csr[adrB];
  }

  float sx = 0.f, sy = 0.f, ssx = 0.f, ssy = 0.f;

#pragma unroll
  for (int p = 0; p < 4; ++p) {
    int rA = i0 + slot * 2 + p * 8;
    int rB = rA + 1;
    int degA = dAs[p], degB = dBs[p];
    float dA = dinv[rA], dB = dinv[rB];

    unsigned int sU = *(const unsigned int*)(g + (size_t)rA * 128 + c0);
    unsigned int sV = *(const unsigned int*)(g + (size_t)rB * 128 + c0);
    float2 accA = make_float2(bf2f((ushort_t)(sU & 0xffffu)),
                              bf2f((ushort_t)(sU >> 16)));
    float2 accB = make_float2(bf2f((ushort_t)(sV & 0xffffu)),
                              bf2f((ushort_t)(sV >> 16)));

    int dAf = min(degA, 64), dBf = min(degB, 64);
    int nc = (max(dAf, dBf) + 7) >> 3;   // 8-edge chunks, 0..8
    if (nc > 0) {
      unsigned int vA[8], vB[8];
      gather8(g, c0, idxA[p], 0, vA);
      gather8(g, c0, idxB[p], 0, vB);
      for (int q = 1; q < nc; ++q) {
        unsigned int wA[8], wB[8];
        gather8(g, c0, idxA[p], q, wA);
        gather8(g, c0, idxB[p], q, wB);
        consume8(accA, vA, q - 1, dAf);
        consume8(accB, vB, q - 1, dBf);
#pragma unroll
        for (int k = 0; k < 8; ++k) { vA[k] = wA[k]; vB[k] = wB[k]; }
      }
      consume8(accA, vA, nc - 1, dAf);
      consume8(accB, vB, nc - 1, dBf);
    }

    // rare tail: degree > 64 (broadcast loads)
    if (degA > 64) {
      int eA = __shfl(offv, slot * 2 + p * 8);
      for (int e = eA + 64; e < eA + degA; ++e) {
        int idx = csr[e];
        unsigned int v = *(const unsigned int*)(g + (size_t)idx * 128 + c0);
        accA.x += bf2f((ushort_t)(v & 0xffffu));
        accA.y += bf2f((ushort_t)(v >> 16));
      }
    }
    if (degB > 64) {
      int eB = __shfl(offv, slot * 2 + p * 8 + 1);
      for (int e = eB + 64; e < eB + degB; ++e) {
        int idx = csr[e];
        unsigned int v = *(const unsigned int*)(g + (size_t)idx * 128 + c0);
        accB.x += bf2f((ushort_t)(v & 0xffffu));
        accB.y += bf2f((ushort_t)(v >> 16));
      }
    }

    accA.x *= dA; accA.y *= dA;
    accB.x *= dB; accB.y *= dB;
    unsigned int oA = (unsigned int)f2bf(accA.x) | ((unsigned int)f2bf(accA.y) << 16);
    unsigned int oB = (unsigned int)f2bf(accB.x) | ((unsigned int)f2bf(accB.y) << 16);
    *(unsigned int*)(outb + (size_t)rA * 128 + c0) = oA;
    *(unsigned int*)(outb + (size_t)rB * 128 + c0) = oB;
    sx += accA.x + accB.x;
    sy += accA.y + accB.y;
    ssx = fmaf(accA.x, accA.x, ssx); ssx = fmaf(accB.x, accB.x, ssx);
    ssy = fmaf(accA.y, accA.y, ssy); ssy = fmaf(accB.y, accB.y, ssy);
  }

  atomicAdd(&ls[c0 + 0], sx);
  atomicAdd(&ls[c0 + 1], sy);
  atomicAdd(&lss[c0 + 0], ssx);
  atomicAdd(&lss[c0 + 1], ssy);
  __syncthreads();
  if (t < 128) {
    atomicAdd(&stats[t], ls[t]);
    atomicAdd(&stats[t + 128], lss[t]);
  }
}

// per-graph mean of relu(bn(A_bf)) for the last layer
__global__ __launch_bounds__(128)
void gk_pool(const ushort_t* __restrict__ A, const float* __restrict__ stats,
             const float* __restrict__ gamma, const float* __restrict__ beta,
             float inv_n, float* __restrict__ z, int npg, int zoff) {
  int gidx = blockIdx.x;
  int c = threadIdx.x;
  float mu = stats[c] * inv_n;
  float var = stats[128 + c] * inv_n - mu * mu;
  float scl = gamma[c] * rsqrtf(var + BN_EPS);
  float be = beta[c];
  float sum = 0.f;
  int r0 = gidx * npg;
  for (int r = 0; r < npg; ++r) {
    float v = (bf2f(A[(size_t)(r0 + r) * 128 + c]) - mu) * scl + be;
    sum += v > 0.f ? v : 0.f;
  }
  z[(size_t)gidx * 256 + zoff + c] = sum * (1.0f / (float)npg);
}

__global__ __launch_bounds__(128)
void gk_mlp(const float* __restrict__ z, const float* __restrict__ w1,
            const float* __restrict__ b1, const float* __restrict__ w2,
            const float* __restrict__ b2, float* __restrict__ out) {
  __shared__ float zs[256];
  __shared__ float red[128];
  int gidx = blockIdx.x, t = threadIdx.x;
  zs[t] = z[(size_t)gidx * 256 + t];
  zs[t + 128] = z[(size_t)gidx * 256 + 128 + t];
  __syncthreads();
  float acc = b1[t];
  for (int k = 0; k < 256; ++k) acc += zs[k] * w1[(size_t)k * 128 + t];
  acc = (acc > 0.f ? acc : 0.f) * w2[t];
  red[t] = acc;
  __syncthreads();
  for (int o = 64; o > 0; o >>= 1) {
    if (t < o) red[t] += red[t + o];
    __syncthreads();
  }
  if (t == 0) out[gidx] = red[0] + b2[0];
}

// ============================ launch ============================

extern "C" void kernel_launch(void* const* d_in, const int* in_sizes, int n_in,
                              void* d_out, int out_size, void* d_ws, size_t ws_size,
                              hipStream_t stream) {
  (void)in_sizes; (void)n_in; (void)out_size; (void)ws_size;
  const int*   lig_x       = (const int*)  d_in[0];
  const int*   rec_x_int   = (const int*)  d_in[1];
  const float* rec_x_float = (const float*)d_in[2];
  const int*   lig_ei      = (const int*)  d_in[3];
  const int*   rec_ei      = (const int*)  d_in[4];
  const int*   atom_off    = (const int*)  d_in[7];
  const float* atom_emb    = (const float*)d_in[8];
  const float* rec_emb1    = (const float*)d_in[9];
  const float* rec_w       = (const float*)d_in[10];
  const float* rec_b       = (const float*)d_in[11];
  const float* lig_W       = (const float*)d_in[12];
  const float* lig_gamma   = (const float*)d_in[14];
  const float* lig_beta    = (const float*)d_in[15];
  const float* rec_W       = (const float*)d_in[16];
  const float* rec_gamma   = (const float*)d_in[18];
  const float* rec_beta    = (const float*)d_in[19];
  const float* out_w1      = (const float*)d_in[20];
  const float* out_b1      = (const float*)d_in[21];
  const float* out_w2      = (const float*)d_in[22];
  const float* out_b2      = (const float*)d_in[23];
  float* out = (float*)d_out;

  char* p = (char*)d_ws;
  auto alloc = [&](size_t bytes) -> void* {
    void* r = p;
    p += (bytes + 255) & ~(size_t)255;
    return r;
  };
  ushort_t* Ab     = (ushort_t*)alloc((size_t)NREC * EMB * 2);  // features bf16
  ushort_t* Gb     = (ushort_t*)alloc((size_t)NREC * EMB * 2);  // g bf16
  ushort_t* Wtb    = (ushort_t*)alloc((size_t)EMB * EMB * 2);   // W^T bf16
  ushort_t* WtK    = (ushort_t*)alloc((size_t)EMB * 224 * 2);   // rec_w^T bf16, K-padded
  ushort_t* Xb2    = (ushort_t*)alloc(((size_t)NREC * 200 + 64) * 2);  // bf16 X, padded rows
  float* bnscl     = (float*)alloc(128 * 4);
  float* bnsh      = (float*)alloc(128 * 4);
  float* dinv_lig  = (float*)alloc((size_t)NLIG * 4);
  float* dinv_rec  = (float*)alloc((size_t)NREC * 4);
  int*   cnt_lig   = (int*)  alloc((size_t)NLIG * 4);
  int*   cnt_rec   = (int*)  alloc((size_t)NREC * 4);
  int*   off_lig   = (int*)  alloc((size_t)(NLIG + 8) * 4);
  int*   off_rec   = (int*)  alloc((size_t)(NREC + 8) * 4);
  int*   csr_lig   = (int*)  alloc((size_t)ELIG * 4);
  int*   csr_rec   = (int*)  alloc((size_t)EREC * 4);
  int*   bsum_lig  = (int*)  alloc(256 * 4);
  int*   bsum_rec  = (int*)  alloc(256 * 4);
  float* stats     = (float*)alloc(256 * 4);
  float* z         = (float*)alloc((size_t)NGRAPH * 256 * 4);

  // ---- CSR build ----
  hipMemsetAsync(cnt_lig, 0, (size_t)NLIG * 4, stream);
  hipMemsetAsync(cnt_rec, 0, (size_t)NREC * 4, stream);
  gk_count<<<ELIG / 256, 256, 0, stream>>>(lig_ei + ELIG, cnt_lig, ELIG);
  gk_count<<<EREC / 256, 256, 0, stream>>>(rec_ei + EREC, cnt_rec, EREC);
  gk_scan1<<<NLIG / 1024, 256, 0, stream>>>(cnt_lig, off_lig, bsum_lig, NLIG);
  gk_scan2<<<1, 256, 0, stream>>>(bsum_lig, NLIG / 1024);
  gk_scan3<<<NLIG / 256, 256, 0, stream>>>(off_lig, bsum_lig, NLIG, ELIG);
  gk_scan1<<<NREC / 1024, 256, 0, stream>>>(cnt_rec, off_rec, bsum_rec, NREC);
  gk_scan2<<<1, 256, 0, stream>>>(bsum_rec, NREC / 1024);
  gk_scan3<<<NREC / 256, 256, 0, stream>>>(off_rec, bsum_rec, NREC, EREC);
  gk_copy<<<NLIG / 256, 256, 0, stream>>>(cnt_lig, off_lig, NLIG);
  gk_copy<<<NREC / 256, 256, 0, stream>>>(cnt_rec, off_rec, NREC);
  gk_fill<<<ELIG / 256, 256, 0, stream>>>(lig_ei, lig_ei + ELIG, cnt_lig, csr_lig, ELIG);
  gk_fill<<<EREC / 256, 256, 0, stream>>>(rec_ei, rec_ei + EREC, cnt_rec, csr_rec, EREC);
  gk_dinv<<<NLIG / 256, 256, 0, stream>>>(off_lig, dinv_lig, NLIG);
  gk_dinv<<<NREC / 256, 256, 0, stream>>>(off_rec, dinv_rec, NREC);

  auto run_entity = [&](const float* Wall, const float* gamma, const float* beta,
                        const int* offv, const int* csrv, const float* dinv,
                        int n, int npg, int zoff) {
    float inv_n = 1.0f / (float)n;
    for (int l = 0; l < 3; ++l) {
      const float* W = Wall + (size_t)l * EMB * EMB;
      const float* gm = (l > 0) ? gamma + (size_t)(l - 1) * EMB : gamma;
      const float* bt = (l > 0) ? beta + (size_t)(l - 1) * EMB : beta;
      gk_prep<<<64, 256, 0, stream>>>(W, stats, gm, bt, inv_n, l > 0 ? 1 : 0,
                                      Wtb, bnscl, bnsh);
      hipMemsetAsync(stats, 0, 256 * 4, stream);
      gk_mm<<<n / 128, 256, 0, stream>>>(Ab, Wtb, bnscl, bnsh, l > 0 ? 1 : 0,
                                         dinv, Gb);
      gk_agg<<<n / 32, 256, 0, stream>>>(Gb, offv, csrv, dinv, Ab, stats);
    }
    gk_pool<<<NGRAPH, 128, 0, stream>>>(Ab, stats, gamma + 2 * EMB, beta + 2 * EMB,
                                        inv_n, z, npg, zoff);
  };

  // ---- ligand path ----
  gk_ligenc<<<NLIG, 128, 0, stream>>>(lig_x, atom_off, atom_emb, Ab);
  run_entity(lig_W, lig_gamma, lig_beta, off_lig, csr_lig, dinv_lig,
             NLIG, NLIG / NGRAPH, 0);

  // ---- receptor path ----
  gk_recw2<<<112, 256, 0, stream>>>(rec_w, WtK);
  gk_xcast<<<2048, 256, 0, stream>>>(rec_x_float, Xb2);
  gk_recenc2<<<NREC / 128, 256, 0, stream>>>(Xb2, rec_x_int, rec_emb1,
                                             WtK, rec_b, Ab);
  run_entity(rec_W, rec_gamma, rec_beta, off_rec, csr_rec, dinv_rec,
             NREC, NREC / NGRAPH, EMB);

  // ---- head ----
  gk_mlp<<<NGRAPH, 128, 0, stream>>>(z, out_w1, out_b1, out_w2, out_b2, out);
}